// Round 10
// baseline (145.051 us; speedup 1.0000x reference)
//
#include <hip/hip_runtime.h>

// Resample2d: backward warp of input1 (B,C,H,W) by flow input2 (B,2,H,W).
// Bilinear, border padding (clamp). B=8 C=64 H=256 W=448, all fp32.
//
// Round 10: LDS-gather, third attempt (R5 died of occupancy, R6 of serial
// vmcnt(0) + window amplification). Global scattered gathers cost ~42cyc/
// wave-instr (TA distinct-line bound, measured R7-R9); ds_read is
// scatter-immune. Design:
//  - block = 112x32 px tile x 16 channels; window = 40 rows x 128 cols fp32
//    (20KB; WF4 = 1280 = 5*256 -> staging is EXEC-UNIFORM: 5 global_load_lds
//    width-16 per thread, so counted vmcnt works per-wave).
//  - double-buffered windows (40KB LDS -> 4 blocks/CU, 16 waves/CU).
//  - T4 counted waits: stage ch c+2 issues after the read barrier and stays
//    in flight across BOTH barriers; vmcnt(19) = 14 nt-stores + 5 gloads.
//  - coords precomputed once: u16/px = byte-offA | yflag<<15; weights (wx,wy)
//    with the x-border folded as wx:=1 (pair base shifted -1).
//  - out-of-window pixels (P~1e-4) take an exact global fallback; its extra
//    vm ops only over-drain the counted vmcnt (safe).

#define RB 8
#define RC 64
#define RH 256
#define RW 448
#define RHW (RH * RW)
#define TPB 256
#define XW 112
#define YW 32
#define CS 4
#define CPB (RC / CS)               // 16
#define NXT (RW / XW)               // 4
#define NYT (RH / YW)               // 8
#define NBLK (RB * CS * NXT * NYT)  // 1024
#define NXCD 8
#define WROWS 40
#define WCOLS 128
#define WFLOATS (WROWS * WCOLS)     // 5120 floats = 20480 B
#define WF4 (WFLOATS / 4)           // 1280 = 5 * 256 (exec-uniform staging)
#define NCHUNK (WF4 / TPB)          // 5
#define PXT ((XW * YW) / TPB)       // 14 pixels per thread

#define GLOAD_LDS16(gp, lp)                                                   \
    __builtin_amdgcn_global_load_lds(                                         \
        (const __attribute__((address_space(1))) void*)(gp),                  \
        (__attribute__((address_space(3))) void*)(lp), 16, 0, 0)

__global__ __launch_bounds__(TPB, 4) void resample2d_kernel(
    const float* __restrict__ img,   // (B,C,H,W)
    const float* __restrict__ flow,  // (B,2,H,W)
    float* __restrict__ out)         // (B,C,H,W)
{
    __shared__ float sm[2][WFLOATS];   // 40960 B

    // Bijective XCD-chunked swizzle (1024 % 8 == 0); consecutive ids sweep
    // y-tiles of one (b,cg,xt) so window halos overlap within one XCD L2.
    int bid = blockIdx.x;
    int id = (bid & (NXCD - 1)) * (NBLK / NXCD) + (bid >> 3);
    int yt = id & 7;
    int xt = (id >> 3) & 3;
    int cg = (id >> 5) & 3;
    int b  = id >> 7;
    int tx = xt * XW, ty = yt * YW;
    int xs0 = min(max((tx - 8) & ~3, 0), RW - WCOLS);   // 4-aligned
    int ys0 = min(max(ty - 4, 0), RH - WROWS);

    int tid = threadIdx.x;
    const float* flb = flow + (size_t)b * 2 * RHW;

    // ---- Coord precompute (channel-invariant) ----
    unsigned pk[(PXT + 1) / 2];        // 2 u16 per reg: offA | yflag<<15
    float wxa[PXT], wya[PXT];
    int po[PXT];                        // within-plane pixel offset
    #pragma unroll
    for (int k = 0; k < PXT; ++k) {
        int p = k * TPB + tid;
        int row = p / XW;
        int col = p - row * XW;
        int y = ty + row, x = tx + col;
        int off = y * RW + x;
        po[k] = off;
        float fx = flb[off];
        float fy = flb[RHW + off];
        float xr = fminf(fmaxf((float)x + fx, 0.f), (float)(RW - 1));
        float yr = fminf(fmaxf((float)y + fy, 0.f), (float)(RH - 1));
        float x0f = floorf(xr), y0f = floorf(yr);
        float wx = xr - x0f, wy = yr - y0f;
        int x0 = (int)x0f, y0 = (int)y0f;
        int shift = (x0 == RW - 1) ? 1 : 0;    // border: pair base -1, wx:=1
        int lx = x0 - xs0 - shift;
        int ly0 = y0 - ys0;
        int yflag = (y0 < RH - 1) ? 1 : 0;
        int ly1 = ly0 + yflag;
        unsigned val;
        if ((unsigned)lx <= WCOLS - 2 && (unsigned)ly0 < WROWS &&
            (unsigned)ly1 < WROWS) {
            unsigned offA = (unsigned)((ly0 * WCOLS + lx) * 4);  // <= 20472
            val = offA | ((unsigned)yflag << 15);
        } else {
            val = 0xFFFFu;                     // outlier sentinel
        }
        wxa[k] = shift ? 1.0f : wx;
        wya[k] = wy;
        if ((k & 1) == 0) pk[k >> 1] = val;
        else              pk[k >> 1] |= (val << 16);
    }

    const float* imgc = img + ((size_t)b * RC + (size_t)cg * CPB) * RHW;
    float* outc       = out + ((size_t)b * RC + (size_t)cg * CPB) * RHW;
    const float* gwin = imgc + (size_t)ys0 * RW + xs0;

    // ---- Prologue: drain, then stage ch0 -> buf0, ch1 -> buf1 ----
    asm volatile("s_waitcnt vmcnt(0)" ::: "memory");
    #pragma unroll
    for (int kk = 0; kk < NCHUNK; ++kk) {
        int f4 = kk * TPB + tid;
        int row = f4 >> 5, c4 = f4 & 31;     // 32 float4 per window row
        GLOAD_LDS16(gwin + row * RW + (c4 << 2), &sm[0][(size_t)f4 << 2]);
    }
    #pragma unroll
    for (int kk = 0; kk < NCHUNK; ++kk) {
        int f4 = kk * TPB + tid;
        int row = f4 >> 5, c4 = f4 & 31;
        GLOAD_LDS16(gwin + RHW + row * RW + (c4 << 2),
                    &sm[1][(size_t)f4 << 2]);
    }
    asm volatile("s_waitcnt vmcnt(5)" ::: "memory");   // buf0's 5 done
    __builtin_amdgcn_s_barrier();
    __builtin_amdgcn_sched_barrier(0);

    #pragma unroll 1
    for (int c = 0; c < CPB; ++c) {
        const float* sb = sm[c & 1];
        float* q = outc + (size_t)c * RHW;

        #pragma unroll
        for (int k = 0; k < PXT; ++k) {
            unsigned pa = (pk[k >> 1] >> ((k & 1) * 16)) & 0xFFFFu;
            float v;
            if (__builtin_expect(pa != 0xFFFFu, 1)) {
                unsigned offA = pa & 0x7FFFu;
                unsigned offB = offA + ((pa >> 15) << 9);   // +512B if yflag
                const char* bp = (const char*)sb;
                float a0 = *(const float*)(bp + offA);
                float a1 = *(const float*)(bp + offA + 4);
                float b0 = *(const float*)(bp + offB);
                float b1 = *(const float*)(bp + offB + 4);
                float vA = a0 + (a1 - a0) * wxa[k];
                float vB = b0 + (b1 - b0) * wxa[k];
                v = vA + (vB - vA) * wya[k];
            } else {
                // Rare exact fallback: recompute from flow, gather global.
                int off = po[k];
                int y = off / RW, x = off - y * RW;
                float fx = flb[off];
                float fy = flb[RHW + off];
                float xr = fminf(fmaxf((float)x + fx, 0.f), (float)(RW - 1));
                float yr = fminf(fmaxf((float)y + fy, 0.f), (float)(RH - 1));
                float x0f = floorf(xr), y0f = floorf(yr);
                float ax = xr - x0f, ay = yr - y0f;
                int x0 = (int)x0f, y0 = (int)y0f;
                int x1 = min(x0 + 1, RW - 1), y1 = min(y0 + 1, RH - 1);
                const float* pp = imgc + (size_t)c * RHW;
                float v00 = pp[y0 * RW + x0], v01 = pp[y0 * RW + x1];
                float v10 = pp[y1 * RW + x0], v11 = pp[y1 * RW + x1];
                float vA = v00 + (v01 - v00) * ax;
                float vB = v10 + (v11 - v10) * ax;
                v = vA + (vB - vA) * ay;
            }
            __builtin_nontemporal_store(v, q + po[k]);
        }

        // All my LDS reads done; barrier => whole block done reading buf.
        asm volatile("s_waitcnt lgkmcnt(0)" ::: "memory");
        __builtin_amdgcn_s_barrier();
        __builtin_amdgcn_sched_barrier(0);

        // Stage channel c+2 into the buffer just freed (clamped: keeps the
        // per-wave vm-op count uniform so the counted vmcnt below is exact).
        {
            int cn = min(c + 2, CPB - 1);
            const float* g = gwin + (size_t)cn * RHW;
            float* dst = sm[c & 1];
            #pragma unroll
            for (int kk = 0; kk < NCHUNK; ++kk) {
                int f4 = kk * TPB + tid;
                int row = f4 >> 5, c4 = f4 & 31;
                GLOAD_LDS16(g + row * RW + (c4 << 2), &dst[(size_t)f4 << 2]);
            }
        }

        // Counted wait: queue = [5 gl(next buf), 14 stores, 5 gl(this buf)]
        // -> vmcnt(19) drains exactly the 5 loads iter c+1 will read.
        asm volatile("s_waitcnt vmcnt(19)" ::: "memory");
        __builtin_amdgcn_s_barrier();
        __builtin_amdgcn_sched_barrier(0);
    }
}

extern "C" void kernel_launch(void* const* d_in, const int* in_sizes, int n_in,
                              void* d_out, int out_size, void* d_ws, size_t ws_size,
                              hipStream_t stream) {
    const float* img  = (const float*)d_in[0];
    const float* flow = (const float*)d_in[1];
    float* out = (float*)d_out;

    resample2d_kernel<<<NBLK, TPB, 0, stream>>>(img, flow, out);
}

// Round 12
// 122.039 us; speedup vs baseline: 1.1886x; 1.1886x over previous
//
#include <hip/hip_runtime.h>

// Resample2d: backward warp of input1 (B,C,H,W) by flow input2 (B,2,H,W).
// Bilinear, border padding (clamp). B=8 C=64 H=256 W=448, all fp32.
//
// Round 12: R11 with the vmcnt race fixed. R11 failed because the counted
// wait assumed 7 stores/iter; actual is PXT=4 (64x16 tile / 256 thr), so
// vmcnt(10) left the previous iteration's staging loads undrained ->
// LDS read-before-DMA-landed race. Correct count: [3 gl(c+2) + 4 stores]
// newer than the loads we must drain -> vmcnt(7). Also pin (D) loads
// before the (E) wait with sched_barrier(0) (compiler sink hazard).
//  - Tile 64x16 px: wave store-row = 256B span, 256B-aligned (no write amp).
//  - Window 32x96 fp32 = 12KB, dbuf = 24KB -> 6 blocks/CU.
//  - 3 exec-uniform global_load_lds(16B)/thread; T4 counted waits; stage
//    c+2 issued right after the read-done barrier (T14).
//  - Outliers (P~1e-9) take an exact global fallback (over-drain safe).

#define RB 8
#define RC 64
#define RH 256
#define RW 448
#define RHW (RH * RW)
#define TPB 256
#define TLX 64
#define TLY 16
#define CS 4
#define CPB (RC / CS)               // 16
#define NXT (RW / TLX)              // 7
#define NYT (RH / TLY)              // 16
#define NBLK (RB * CS * NYT * NXT)  // 3584
#define NXCD 8
#define WR 32                       // window rows
#define WC 96                       // window cols (floats)
#define WFLOATS (WR * WC)           // 3072 = 12288 B
#define WF4 (WFLOATS / 4)           // 768 = 3 * 256
#define NCHUNK (WF4 / TPB)          // 3
#define PXT ((TLX * TLY) / TPB)     // 4 pixels per thread

#define GLOAD_LDS16(gp, lp)                                                   \
    __builtin_amdgcn_global_load_lds(                                         \
        (const __attribute__((address_space(1))) void*)(gp),                  \
        (__attribute__((address_space(3))) void*)(lp), 16, 0, 0)

__global__ __launch_bounds__(TPB, 6) void resample2d_kernel(
    const float* __restrict__ img,   // (B,C,H,W)
    const float* __restrict__ flow,  // (B,2,H,W)
    float* __restrict__ out)         // (B,C,H,W)
{
    __shared__ float sm[2][WFLOATS];   // 24576 B

    // Bijective XCD-chunked swizzle (3584 % 8 == 0). id minor-orders xt,
    // then yt, then cg, then b: each XCD chunk = 448 consecutive tiles.
    int bid = blockIdx.x;
    int id = (bid & (NXCD - 1)) * (NBLK / NXCD) + (bid >> 3);
    int xt = id % NXT;
    int t2 = id / NXT;
    int yt = t2 % NYT;
    int t3 = t2 / NYT;
    int cg = t3 % CS;
    int b  = t3 / CS;

    int tx = xt * TLX, ty = yt * TLY;
    int xs0 = min(max(tx - 16, 0), RW - WC);   // 16-float aligned
    int ys0 = min(max(ty - 8, 0),  RH - WR);

    int tid = threadIdx.x;
    const float* flb = flow + (size_t)b * 2 * RHW;

    // ---- Coord precompute (channel-invariant) ----
    unsigned offAB[PXT];       // byte offA | yflag<<15  (offA <= 12280)
    float wxa[PXT], wya[PXT];
    int po[PXT];               // within-plane pixel offset
    #pragma unroll
    for (int k = 0; k < PXT; ++k) {
        int row = k * 4 + (tid >> 6);          // wave = one tile row
        int col = tid & 63;
        int y = ty + row, x = tx + col;
        int off = y * RW + x;
        po[k] = off;
        float fx = flb[off];
        float fy = flb[RHW + off];
        float xr = fminf(fmaxf((float)x + fx, 0.f), (float)(RW - 1));
        float yr = fminf(fmaxf((float)y + fy, 0.f), (float)(RH - 1));
        float x0f = floorf(xr), y0f = floorf(yr);
        float wx = xr - x0f, wy = yr - y0f;
        int x0 = (int)x0f, y0 = (int)y0f;
        int shift = (x0 == RW - 1) ? 1 : 0;    // border: pair base -1, wx:=1
        int lx = x0 - xs0 - shift;
        int ly0 = y0 - ys0;
        int yflag = (y0 < RH - 1) ? 1 : 0;
        unsigned val;
        if ((unsigned)lx <= WC - 2 && (unsigned)ly0 < WR &&
            (unsigned)(ly0 + yflag) < WR) {
            val = (unsigned)((ly0 * WC + lx) * 4) | ((unsigned)yflag << 15);
        } else {
            val = 0xFFFFFFFFu;                 // outlier sentinel
        }
        offAB[k] = val;
        wxa[k] = shift ? 1.0f : wx;
        wya[k] = wy;
    }

    const float* imgc = img + ((size_t)b * RC + (size_t)cg * CPB) * RHW;
    float* outc       = out + ((size_t)b * RC + (size_t)cg * CPB) * RHW;
    const float* gwin = imgc + (size_t)ys0 * RW + xs0;

    // Staging offsets, computed once: f4 = kk*256+tid -> (row, c4).
    // LDS dest per wave is base + lane*16 (linear) as global_load_lds needs.
    int srcOff[NCHUNK], ldsOff[NCHUNK];
    #pragma unroll
    for (int kk = 0; kk < NCHUNK; ++kk) {
        int f4 = kk * TPB + tid;
        int row = f4 / (WC / 4);               // /24
        int c4  = f4 - row * (WC / 4);
        srcOff[kk] = row * RW + c4 * 4;        // float offset in global
        ldsOff[kk] = f4 * 4;                   // float offset in LDS
    }

    // ---- Prologue: stage ch0 -> buf0, ch1 -> buf1 ----
    asm volatile("s_waitcnt vmcnt(0)" ::: "memory");
    #pragma unroll
    for (int kk = 0; kk < NCHUNK; ++kk)
        GLOAD_LDS16(gwin + srcOff[kk], &sm[0][ldsOff[kk]]);
    #pragma unroll
    for (int kk = 0; kk < NCHUNK; ++kk)
        GLOAD_LDS16(gwin + RHW + srcOff[kk], &sm[1][ldsOff[kk]]);
    __builtin_amdgcn_sched_barrier(0);
    asm volatile("s_waitcnt vmcnt(3)" ::: "memory");   // buf0 ready
    __builtin_amdgcn_s_barrier();
    __builtin_amdgcn_sched_barrier(0);

    #pragma unroll 1
    for (int c = 0; c < CPB; ++c) {
        const float* sb = sm[c & 1];
        float* q = outc + (size_t)c * RHW;

        // (A) gather from LDS + blend + aligned nt-store (4 per thread).
        #pragma unroll
        for (int k = 0; k < PXT; ++k) {
            unsigned v4 = offAB[k];
            float v;
            if (__builtin_expect(v4 != 0xFFFFFFFFu, 1)) {
                unsigned offA = v4 & 0x7FFFu;
                unsigned offB = offA + ((v4 >> 15) ? (unsigned)(WC * 4) : 0u);
                const char* bp = (const char*)sb;
                float a0 = *(const float*)(bp + offA);
                float a1 = *(const float*)(bp + offA + 4);
                float b0 = *(const float*)(bp + offB);
                float b1 = *(const float*)(bp + offB + 4);
                float vA = a0 + (a1 - a0) * wxa[k];
                float vB = b0 + (b1 - b0) * wxa[k];
                v = vA + (vB - vA) * wya[k];
            } else {
                // Exact fallback (P ~ 1e-9): recompute, gather global.
                int off = po[k];
                int y = off / RW, x = off - y * RW;
                float fx = flb[off];
                float fy = flb[RHW + off];
                float xr = fminf(fmaxf((float)x + fx, 0.f), (float)(RW - 1));
                float yr = fminf(fmaxf((float)y + fy, 0.f), (float)(RH - 1));
                float x0f = floorf(xr), y0f = floorf(yr);
                float ax = xr - x0f, ay = yr - y0f;
                int x0 = (int)x0f, y0 = (int)y0f;
                int x1 = min(x0 + 1, RW - 1), y1 = min(y0 + 1, RH - 1);
                const float* pp = imgc + (size_t)c * RHW;
                float v00 = pp[y0 * RW + x0], v01 = pp[y0 * RW + x1];
                float v10 = pp[y1 * RW + x0], v11 = pp[y1 * RW + x1];
                float vA = v00 + (v01 - v00) * ax;
                float vB = v10 + (v11 - v10) * ax;
                v = vA + (vB - vA) * ay;
            }
            __builtin_nontemporal_store(v, q + po[k]);
        }

        // (C) block done reading buf[c&1].
        asm volatile("s_waitcnt lgkmcnt(0)" ::: "memory");
        __builtin_amdgcn_s_barrier();
        __builtin_amdgcn_sched_barrier(0);

        // (D) stage ch c+2 into the freed buffer (clamped: uniform vm count).
        {
            int cn = min(c + 2, CPB - 1);
            const float* g = gwin + (size_t)cn * RHW;
            float* dst = sm[c & 1];
            #pragma unroll
            for (int kk = 0; kk < NCHUNK; ++kk)
                GLOAD_LDS16(g + srcOff[kk], &dst[ldsOff[kk]]);
        }
        __builtin_amdgcn_sched_barrier(0);   // pin (D) before the wait

        // (E) counted wait. Queue newest-first: [3 gl(c+2), 4 stores(c),
        //     3 gl(c+1), ...]. vmcnt(7) leaves the newest 7 -> drains
        //     everything through iter c-1's staging loads (iter c+1's buf).
        asm volatile("s_waitcnt vmcnt(7)" ::: "memory");
        __builtin_amdgcn_s_barrier();
        __builtin_amdgcn_sched_barrier(0);
    }
}

extern "C" void kernel_launch(void* const* d_in, const int* in_sizes, int n_in,
                              void* d_out, int out_size, void* d_ws, size_t ws_size,
                              hipStream_t stream) {
    const float* img  = (const float*)d_in[0];
    const float* flow = (const float*)d_in[1];
    float* out = (float*)d_out;

    resample2d_kernel<<<NBLK, TPB, 0, stream>>>(img, flow, out);
}